// Round 9
// baseline (1598.874 us; speedup 1.0000x reference)
//
#include <hip/hip_runtime.h>
#include <hip/hip_fp16.h>
#include <math.h>

// Build pipeline = round 7 (windowed keys). Propagation: 4 feature slices of
// 16 (3.2 MB each); grid is laid out in 4 contiguous blockIdx BANDS so the
// whole GPU sweeps slice 0 -> 1 -> 2 -> 3 in rough dispatch order. The active
// gather set at any instant is one ~3.2 MB slice -> read-only replicated in
// every XCD's 4 MB L2 -> gathers hit local L2 instead of the ~5 TB/s fabric.
// (Dispatch order affects only speed; every (row,slice) is statically covered.)

#define WSH 14
#define KSH 3

// ---------------- init / histogram / norm ----------------

__global__ void zero_i32(int* __restrict__ p, int n) {
    int i = blockIdx.x * blockDim.x + threadIdx.x;
    if (i < n) p[i] = 0;
}

__global__ void hist_k(const int* __restrict__ src, const int* __restrict__ dst,
                       int E, int* __restrict__ counts) {
    int e = blockIdx.x * blockDim.x + threadIdx.x;
    if (e < E) {
        int key = (dst[e] << KSH) | (src[e] >> WSH);
        atomicAdd(&counts[key], 1);
    }
}

__global__ void dinv_k(const int* __restrict__ rowptr, float* __restrict__ dinv, int N) {
    int i = blockIdx.x * blockDim.x + threadIdx.x;
    if (i < N) {
        int deg = rowptr[(i + 1) << KSH] - rowptr[i << KSH];
        dinv[i] = rsqrtf((float)(deg + 1));  // +1 self-loop
    }
}

// zero dummy row N (4 slices x 8 half2) of the three gather buffers
__global__ void zero_dummy(__half2* __restrict__ b0, __half2* __restrict__ b1,
                           __half2* __restrict__ b2, int N) {
    int t = threadIdx.x;
    if (t >= 96) return;
    __half2* b = (t < 32) ? b0 : (t < 64) ? b1 : b2;
    int r = t & 31, s = r >> 3, h = r & 7;
    b[((size_t)s * (N + 1) + N) * 8 + h] = __floats2half2_rn(0.f, 0.f);
}

// ---------------- 3-pass exclusive scan over nk elems ----------------

__global__ void scan_pass1(const int* __restrict__ counts, int n, int* __restrict__ bsum) {
    __shared__ int s[256];
    int t = threadIdx.x;
    int base = blockIdx.x * 1024 + t * 4;
    int sum = 0;
    for (int j = 0; j < 4; ++j) { int i = base + j; if (i < n) sum += counts[i]; }
    s[t] = sum; __syncthreads();
    for (int off = 128; off > 0; off >>= 1) {
        if (t < off) s[t] += s[t + off];
        __syncthreads();
    }
    if (t == 0) bsum[blockIdx.x] = s[0];
}

__global__ void scan_pass2(const int* __restrict__ bsum, int nb, int* __restrict__ boff) {
    __shared__ int s[256];
    int t = threadIdx.x;
    int C = (nb + 255) / 256;
    int b0 = t * C;
    int loc[8]; int sum = 0;
    for (int i = 0; i < C; ++i) {
        int v = (b0 + i < nb) ? bsum[b0 + i] : 0;
        loc[i] = sum; sum += v;
    }
    s[t] = sum; __syncthreads();
    for (int off = 1; off < 256; off <<= 1) {
        int v = (t >= off) ? s[t - off] : 0;
        __syncthreads();
        s[t] += v;
        __syncthreads();
    }
    int excl = s[t] - sum;
    for (int i = 0; i < C; ++i)
        if (b0 + i < nb) boff[b0 + i] = excl + loc[i];
}

__global__ void scan_pass3(const int* __restrict__ counts, int n,
                           const int* __restrict__ boff, int* __restrict__ rowptr, int E) {
    __shared__ int s[256];
    int t = threadIdx.x;
    int base = blockIdx.x * 1024 + t * 4;
    int c[4]; int sum = 0;
    for (int j = 0; j < 4; ++j) { int i = base + j; c[j] = (i < n) ? counts[i] : 0; sum += c[j]; }
    s[t] = sum; __syncthreads();
    for (int off = 1; off < 256; off <<= 1) {
        int v = (t >= off) ? s[t - off] : 0;
        __syncthreads();
        s[t] += v;
        __syncthreads();
    }
    int excl = s[t] - sum + boff[blockIdx.x];
    for (int j = 0; j < 4; ++j) {
        int i = base + j;
        if (i < n) { rowptr[i] = excl; excl += c[j]; }
    }
    if (blockIdx.x == 0 && t == 0) rowptr[n] = E;
}

// ---------------- CSR fill: col index only (4B scatter) ----------------

__global__ void fill_k(const int* __restrict__ src, const int* __restrict__ dst, int E,
                       const int* __restrict__ rowptr,
                       int* __restrict__ cursor, int* __restrict__ col) {
    int e = blockIdx.x * blockDim.x + threadIdx.x;
    if (e >= E) return;
    int s = src[e], d = dst[e];
    int key = (d << KSH) | (s >> WSH);
    int pos = rowptr[key] + atomicAdd(&cursor[key], 1);
    col[pos] = s;
}

// ---------------- g0 = x @ W : LDS-tiled ----------------
// Emits fp32 g0 (teleport) and prescaled fp16 SLICED gather buffer:
// gh0[s][(n)*8 + h] = dinv[n] * g0[n, 16s + 2h .. +1].

__global__ void __launch_bounds__(256) gemm_k(const float* __restrict__ x,
                                              const float* __restrict__ W,
                                              const float* __restrict__ dinv,
                                              float* __restrict__ g0,
                                              __half2* __restrict__ gh0, int N) {
    __shared__ float Ws[128 * 64];
    __shared__ float xs[128 * 133];
    int t = threadIdx.x;
    for (int i = t; i < 128 * 64; i += 256) Ws[i] = W[i];
    int n0 = blockIdx.x * 128;
    for (int f = t; f < 128 * 32; f += 256) {
        int r = f >> 5, c4 = f & 31;
        int n = n0 + r;
        float4 v = (n < N) ? ((const float4*)x)[(size_t)n * 32 + c4]
                           : make_float4(0.f, 0.f, 0.f, 0.f);
        float* dp = &xs[r * 133 + c4 * 4];
        dp[0] = v.x; dp[1] = v.y; dp[2] = v.z; dp[3] = v.w;
    }
    __syncthreads();
    int tr = t & 15, tc = t >> 4;
    int j0 = tr * 4, r0 = tc * 8;
    float acc[8][4] = {};
#pragma unroll 4
    for (int k = 0; k < 128; ++k) {
        float4 wv = *(const float4*)&Ws[k * 64 + j0];
#pragma unroll
        for (int i = 0; i < 8; ++i) {
            float xv = xs[(r0 + i) * 133 + k];
            acc[i][0] += xv * wv.x; acc[i][1] += xv * wv.y;
            acc[i][2] += xv * wv.z; acc[i][3] += xv * wv.w;
        }
    }
    int sl = j0 >> 4, h0 = (j0 & 15) >> 1;
#pragma unroll
    for (int i = 0; i < 8; ++i) {
        int n = n0 + r0 + i;
        if (n < N) {
            float4 v = make_float4(acc[i][0], acc[i][1], acc[i][2], acc[i][3]);
            *(float4*)&g0[(size_t)n * 64 + j0] = v;
            float dn = dinv[n];
            __half2* gp = &gh0[((size_t)sl * (N + 1) + n) * 8 + h0];
            gp[0] = __floats2half2_rn(v.x * dn, v.y * dn);
            gp[1] = __floats2half2_rn(v.z * dn, v.w * dn);
        }
    }
}

// ---------------- propagation (slice-banded grid) ----------------
// slice = blockIdx / nrb  (4 contiguous bands -> GPU sweeps slices in order).
// One wave per (row, slice); 8 half2 lanes per edge -> 8 edges per gather.
// 32 edges (4 gathers) in flight; tails masked via zeroed dummy row N.

__global__ void __launch_bounds__(256) prop_k(const __half2* __restrict__ gin,
                                              const float* __restrict__ g0,
                                              __half2* __restrict__ gout,
                                              float* __restrict__ outf,
                                              const int* __restrict__ rowptr,
                                              const int* __restrict__ cols,
                                              const float* __restrict__ dinv,
                                              const float* __restrict__ bias,
                                              int N, int nrb, int final_step) {
    int slice = blockIdx.x / nrb;
    int row = (blockIdx.x - slice * nrb) * 4 + (threadIdx.x >> 6);
    if (row >= N) return;
    int lane = threadIdx.x & 63;
    int grp = lane >> 3, lf = lane & 7;         // 8 edge-groups x 8 half2 lanes

    const __half2* gs = gin + (size_t)slice * (N + 1) * 8;
    int beg = rowptr[row << KSH];
    int end = rowptr[(row + 1) << KSH];
    int deg = end - beg;

    // hoisted epilogue operands (overlap with gather latency)
    float di   = dinv[row];
    float2 gi  = __half22float2(gs[(size_t)row * 8 + lf]);
    float2 g0v = ((const float2*)g0)[(size_t)row * 32 + slice * 8 + lf];

    float ax = 0.f, ay = 0.f;

    for (int base = 0; base < deg; base += 64) {
        int m = deg - base; if (m > 64) m = 64;
        int idx = beg + base + (lane < m ? lane : 0);
        int ci = cols[idx];                      // 64 edge cols, one load
        int full = m & ~31;
        int j = 0;
        for (; j < full; j += 32) {              // 32 edges, 4 gathers in flight
            float2 f[4];
#pragma unroll
            for (int u = 0; u < 4; ++u) {
                int c = __shfl(ci, j + 8 * u + grp, 64);
                f[u] = __half22float2(gs[(size_t)c * 8 + lf]);
            }
#pragma unroll
            for (int u = 0; u < 4; ++u) { ax += f[u].x; ay += f[u].y; }
        }
        if (j < m) {                             // masked tail (<32 edges)
            float2 f[4];
#pragma unroll
            for (int u = 0; u < 4; ++u) {
                int e = j + 8 * u + grp;
                int c = __shfl(ci, e < 63 ? e : 63, 64);
                if (e >= m) c = N;               // dummy zero row
                f[u] = __half22float2(gs[(size_t)c * 8 + lf]);
            }
#pragma unroll
            for (int u = 0; u < 4; ++u) { ax += f[u].x; ay += f[u].y; }
        }
    }

    // reduce the 8 edge-groups (butterfly over lane bits 3,4,5)
    ax += __shfl(ax, lane ^ 8, 64);  ay += __shfl(ay, lane ^ 8, 64);
    ax += __shfl(ax, lane ^ 16, 64); ay += __shfl(ay, lane ^ 16, 64);
    ax += __shfl(ax, lane ^ 32, 64); ay += __shfl(ay, lane ^ 32, 64);

    if (grp == 0) {
        float rx = 0.9f * di * (ax + gi.x) + 0.1f * g0v.x;
        float ry = 0.9f * di * (ay + gi.y) + 0.1f * g0v.y;
        if (final_step) {
            float2 bv = ((const float2*)bias)[slice * 8 + lf];
            ((float2*)outf)[(size_t)row * 32 + slice * 8 + lf] =
                make_float2(rx + bv.x, ry + bv.y);
        } else {
            __half2* go = gout + (size_t)slice * (N + 1) * 8;
            go[(size_t)row * 8 + lf] = __floats2half2_rn(di * rx, di * ry);
        }
    }
}

// ---------------- launch ----------------

extern "C" void kernel_launch(void* const* d_in, const int* in_sizes, int n_in,
                              void* d_out, int out_size, void* d_ws, size_t ws_size,
                              hipStream_t stream) {
    const float* x  = (const float*)d_in[0];
    const int*   ei = (const int*)d_in[1];
    const float* W  = (const float*)d_in[2];
    const float* b  = (const float*)d_in[3];
    float* out = (float*)d_out;

    const int N = in_sizes[0] / 128;
    const int E = in_sizes[1] / 2;
    const int* src = ei;
    const int* dst = ei + E;
    const int nk = (N + 1) << KSH;

    char* w = (char*)d_ws;
    size_t off = 0;
    auto alloc = [&](size_t bytes) -> void* {
        void* p = w + off;
        off += (bytes + 255) & ~(size_t)255;
        return p;
    };
    const size_t buf_h2 = (size_t)(N + 1) * 32;            // 4 slices x 8 half2
    float*   g0     = (float*)  alloc((size_t)N * 64 * 4);
    __half2* gh0    = (__half2*)alloc(buf_h2 * 4);
    __half2* bufA   = (__half2*)alloc(buf_h2 * 4);
    __half2* bufB   = (__half2*)alloc(buf_h2 * 4);
    int*     cols   = (int*)    alloc((size_t)E * 4);
    int*     rowptr = (int*)    alloc((size_t)(nk + 1) * 4);
    int*     counts = (int*)    alloc((size_t)nk * 4);
    float*   dinvv  = (float*)  alloc((size_t)N * 4);
    const int nb = (nk + 1023) / 1024;
    int*     bsum   = (int*)    alloc((size_t)nb * 4);
    int*     boff   = (int*)    alloc((size_t)nb * 4);

    const int nblkN = (N + 255) / 256;
    const int nblkK = (nk + 255) / 256;
    const int nblkE = (E + 255) / 256;

    zero_i32<<<nblkK, 256, 0, stream>>>(counts, nk);
    hist_k<<<nblkE, 256, 0, stream>>>(src, dst, E, counts);
    zero_dummy<<<1, 96, 0, stream>>>(gh0, bufA, bufB, N);
    scan_pass1<<<nb, 256, 0, stream>>>(counts, nk, bsum);
    scan_pass2<<<1, 256, 0, stream>>>(bsum, nb, boff);
    scan_pass3<<<nb, 256, 0, stream>>>(counts, nk, boff, rowptr, E);
    dinv_k<<<nblkN, 256, 0, stream>>>(rowptr, dinvv, N);
    zero_i32<<<nblkK, 256, 0, stream>>>(counts, nk);
    fill_k<<<nblkE, 256, 0, stream>>>(src, dst, E, rowptr, counts, cols);

    gemm_k<<<(N + 127) / 128, 256, 0, stream>>>(x, W, dinvv, g0, gh0, N);

    // K = 10 APPNP steps; grid = 4 slice-bands x nrb row-blocks
    const int nrb = (N + 3) / 4;
    const int gridP = nrb * 4;
    const __half2* gin = gh0;
    __half2* pp[2] = {bufA, bufB};
    for (int k = 0; k < 10; ++k) {
        const bool fin = (k == 9);
        __half2* gout = pp[k & 1];
        prop_k<<<gridP, 256, 0, stream>>>(gin, g0, gout, out, rowptr, cols,
                                          dinvv, b, N, nrb, fin ? 1 : 0);
        gin = gout;
    }
}

// Round 11
// 1025.239 us; speedup vs baseline: 1.5595x; 1.5595x over previous
//
#include <hip/hip_runtime.h>
#include <hip/hip_fp16.h>
#include <math.h>

// Plain dst-CSR built in two L2-local passes:
//   binsort_k: bin edges by bucket = dst>>8 (256 dsts/bucket), append runs
//              contiguously per bucket (packed rec = src<<8 | dst&255).
//   fill2_k:   one block per bucket; scatter col[] within a ~32KB segment ->
//              write-amp absorbed by that XCD's L2.
// Propagation = round-7 structure (full 128B fp16 rows, readlane broadcast,
// paired gathers), teleport term read from an fp16 g0 copy.
// (Round-10 crash was halved buffer allocations - bytes vs half2 confusion.)

#define BSH 8   // 256 dsts per bucket

// ---------------- init / histogram / norm ----------------

__global__ void zero_i32(int* __restrict__ p, int n) {
    int i = blockIdx.x * blockDim.x + threadIdx.x;
    if (i < n) p[i] = 0;
}

__global__ void hist_k(const int* __restrict__ dst, int E, int* __restrict__ counts) {
    int e = blockIdx.x * blockDim.x + threadIdx.x;
    if (e < E) atomicAdd(&counts[dst[e]], 1);
}

__global__ void dinv_k(const int* __restrict__ rowptr, float* __restrict__ dinv, int N) {
    int i = blockIdx.x * blockDim.x + threadIdx.x;
    if (i < N) {
        int deg = rowptr[i + 1] - rowptr[i];
        dinv[i] = rsqrtf((float)(deg + 1));  // +1 self-loop
    }
}

// zero dummy row N (32 half2) of the three gather buffers
__global__ void zero_dummy(__half2* __restrict__ b0, __half2* __restrict__ b1,
                           __half2* __restrict__ b2, int N) {
    int t = threadIdx.x;
    if (t >= 96) return;
    __half2* b = (t < 32) ? b0 : (t < 64) ? b1 : b2;
    b[(size_t)N * 32 + (t & 31)] = __floats2half2_rn(0.f, 0.f);
}

// prefill scatter cursors: cursor2 = rowptr (per dst); bktcur (padded x16) = bucket base
__global__ void prefill_k(const int* __restrict__ rowptr, int N, int NB,
                          int* __restrict__ cursor2, int* __restrict__ bktcur) {
    int i = blockIdx.x * blockDim.x + threadIdx.x;
    if (i < N) cursor2[i] = rowptr[i];
    if (i < NB) {
        int r = i << BSH; if (r > N) r = N;
        bktcur[i * 16] = rowptr[r];
    }
}

// ---------------- 3-pass exclusive scan over N elems ----------------

__global__ void scan_pass1(const int* __restrict__ counts, int n, int* __restrict__ bsum) {
    __shared__ int s[256];
    int t = threadIdx.x;
    int base = blockIdx.x * 1024 + t * 4;
    int sum = 0;
    for (int j = 0; j < 4; ++j) { int i = base + j; if (i < n) sum += counts[i]; }
    s[t] = sum; __syncthreads();
    for (int off = 128; off > 0; off >>= 1) {
        if (t < off) s[t] += s[t + off];
        __syncthreads();
    }
    if (t == 0) bsum[blockIdx.x] = s[0];
}

__global__ void scan_pass2(const int* __restrict__ bsum, int nb, int* __restrict__ boff) {
    __shared__ int s[256];
    int t = threadIdx.x;
    int C = (nb + 255) / 256;
    int b0 = t * C;
    int loc[8]; int sum = 0;
    for (int i = 0; i < C; ++i) {
        int v = (b0 + i < nb) ? bsum[b0 + i] : 0;
        loc[i] = sum; sum += v;
    }
    s[t] = sum; __syncthreads();
    for (int off = 1; off < 256; off <<= 1) {
        int v = (t >= off) ? s[t - off] : 0;
        __syncthreads();
        s[t] += v;
        __syncthreads();
    }
    int excl = s[t] - sum;
    for (int i = 0; i < C; ++i)
        if (b0 + i < nb) boff[b0 + i] = excl + loc[i];
}

__global__ void scan_pass3(const int* __restrict__ counts, int n,
                           const int* __restrict__ boff, int* __restrict__ rowptr, int E) {
    __shared__ int s[256];
    int t = threadIdx.x;
    int base = blockIdx.x * 1024 + t * 4;
    int c[4]; int sum = 0;
    for (int j = 0; j < 4; ++j) { int i = base + j; c[j] = (i < n) ? counts[i] : 0; sum += c[j]; }
    s[t] = sum; __syncthreads();
    for (int off = 1; off < 256; off <<= 1) {
        int v = (t >= off) ? s[t - off] : 0;
        __syncthreads();
        s[t] += v;
        __syncthreads();
    }
    int excl = s[t] - sum + boff[blockIdx.x];
    for (int j = 0; j < 4; ++j) {
        int i = base + j;
        if (i < n) { rowptr[i] = excl; excl += c[j]; }
    }
    if (blockIdx.x == 0 && t == 0) rowptr[n] = E;
}

// ---------------- pass 1: bin edges by bucket (dst>>8), contiguous runs ----------------

__global__ void __launch_bounds__(256) binsort_k(const int* __restrict__ src,
                                                 const int* __restrict__ dst, int E,
                                                 int* __restrict__ bktcur,  // padded x16
                                                 unsigned* __restrict__ binned) {
    __shared__ int hist[400], gbase[400], lcur[400];
    int t = threadIdx.x;
    for (int i = t; i < 400; i += 256) { hist[i] = 0; lcur[i] = 0; }
    __syncthreads();

    int e0 = blockIdx.x * 4096 + t;
    unsigned rec[16]; int bk[16];
#pragma unroll
    for (int i = 0; i < 16; ++i) {
        int e = e0 + i * 256;
        if (e < E) {
            int s = src[e], d = dst[e];
            bk[i]  = d >> BSH;
            rec[i] = ((unsigned)s << BSH) | (unsigned)(d & 255);
            atomicAdd(&hist[bk[i]], 1);
        } else bk[i] = -1;
    }
    __syncthreads();
    for (int b = t; b < 400; b += 256) {
        int c = hist[b];
        if (c > 0) gbase[b] = atomicAdd(&bktcur[b * 16], c);
    }
    __syncthreads();
#pragma unroll
    for (int i = 0; i < 16; ++i) {
        if (bk[i] >= 0) {
            int loc = atomicAdd(&lcur[bk[i]], 1);
            binned[gbase[bk[i]] + loc] = rec[i];
        }
    }
}

// ---------------- pass 2: per-bucket CSR fill (L2-local scatter) ----------------

__global__ void fill2_k(const unsigned* __restrict__ binned,
                        const int* __restrict__ rowptr, int N,
                        int* __restrict__ cursor2, int* __restrict__ col) {
    int b = blockIdx.x;
    int r0 = b << BSH;       if (r0 > N) r0 = N;
    int r1 = (b + 1) << BSH; if (r1 > N) r1 = N;
    int beg = rowptr[r0], end = rowptr[r1];
    int dbase = b << BSH;
    for (int i = beg + threadIdx.x; i < end; i += blockDim.x) {
        unsigned r = binned[i];
        int d = dbase + (int)(r & 255u);
        int s = (int)(r >> BSH);
        int pos = atomicAdd(&cursor2[d], 1);
        col[pos] = s;
    }
}

// ---------------- g0 = x @ W : LDS-tiled ----------------
// Emits TWO fp16 buffers: g0h = dinv[n]*g0[n] (gather state, +dummy row) and
// g0f = g0[n] (teleport term).

__global__ void __launch_bounds__(256) gemm_k(const float* __restrict__ x,
                                              const float* __restrict__ W,
                                              const float* __restrict__ dinv,
                                              __half2* __restrict__ g0f,
                                              __half2* __restrict__ g0h, int N) {
    __shared__ float Ws[128 * 64];
    __shared__ float xs[128 * 133];
    int t = threadIdx.x;
    for (int i = t; i < 128 * 64; i += 256) Ws[i] = W[i];
    int n0 = blockIdx.x * 128;
    for (int f = t; f < 128 * 32; f += 256) {
        int r = f >> 5, c4 = f & 31;
        int n = n0 + r;
        float4 v = (n < N) ? ((const float4*)x)[(size_t)n * 32 + c4]
                           : make_float4(0.f, 0.f, 0.f, 0.f);
        float* dp = &xs[r * 133 + c4 * 4];
        dp[0] = v.x; dp[1] = v.y; dp[2] = v.z; dp[3] = v.w;
    }
    __syncthreads();
    int tr = t & 15, tc = t >> 4;
    int j0 = tr * 4, r0 = tc * 8;
    float acc[8][4] = {};
#pragma unroll 4
    for (int k = 0; k < 128; ++k) {
        float4 wv = *(const float4*)&Ws[k * 64 + j0];
#pragma unroll
        for (int i = 0; i < 8; ++i) {
            float xv = xs[(r0 + i) * 133 + k];
            acc[i][0] += xv * wv.x; acc[i][1] += xv * wv.y;
            acc[i][2] += xv * wv.z; acc[i][3] += xv * wv.w;
        }
    }
    int h0 = j0 >> 1;
#pragma unroll
    for (int i = 0; i < 8; ++i) {
        int n = n0 + r0 + i;
        if (n < N) {
            float dn = dinv[n];
            __half2* gf = &g0f[(size_t)n * 32 + h0];
            gf[0] = __floats2half2_rn(acc[i][0], acc[i][1]);
            gf[1] = __floats2half2_rn(acc[i][2], acc[i][3]);
            __half2* gp = &g0h[(size_t)n * 32 + h0];
            gp[0] = __floats2half2_rn(acc[i][0] * dn, acc[i][1] * dn);
            gp[1] = __floats2half2_rn(acc[i][2] * dn, acc[i][3] * dn);
        }
    }
}

// ---------------- propagation ----------------
// g_hat = dinv[n]*h[n], fp16 rows of 128 B. One wave per dst row; lanes 0-31
// even edges, 32-63 odd edges. 8 edges (4 paired gathers) per iteration with
// early exit; masked tail via zeroed dummy row N.

__global__ void __launch_bounds__(256) prop_k(const __half2* __restrict__ gin,
                                              const __half2* __restrict__ g0f,
                                              __half2* __restrict__ gout,
                                              float* __restrict__ outf,
                                              const int* __restrict__ rowptr,
                                              const int* __restrict__ cols,
                                              const float* __restrict__ dinv,
                                              const float* __restrict__ bias,
                                              int N, int final_step) {
    int gw = (blockIdx.x * blockDim.x + threadIdx.x) >> 6;
    int lane = threadIdx.x & 63;
    if (gw >= N) return;
    int lh   = lane & 31;   // half2 index within the row
    int pair = lane >> 5;   // 0 = even edge, 1 = odd edge

    int beg = rowptr[gw], end = rowptr[gw + 1];
    int deg = end - beg;

    // hoisted epilogue operands (overlap with gather latency)
    float di   = dinv[gw];
    float2 gi  = __half22float2(gin[(size_t)gw * 32 + lh]);   // self-loop term
    float2 g0v = __half22float2(g0f[(size_t)gw * 32 + lh]);   // teleport term

    float ax = 0.f, ay = 0.f;

    for (int base = 0; base < deg; base += 64) {
        int m = deg - base; if (m > 64) m = 64;
        int idx = beg + base + (lane < m ? lane : 0);
        int ci = cols[idx];                       // 64 edge cols, one load
        int j = 0;
        for (; j + 7 < m; j += 8) {               // 8 edges, 4 paired gathers
            float2 f[4];
#pragma unroll
            for (int u = 0; u < 4; ++u) {
                int ce = __builtin_amdgcn_readlane(ci, j + 2 * u);
                int co = __builtin_amdgcn_readlane(ci, j + 2 * u + 1);
                int c  = pair ? co : ce;
                f[u] = __half22float2(gin[(size_t)c * 32 + lh]);
            }
#pragma unroll
            for (int u = 0; u < 4; ++u) { ax += f[u].x; ay += f[u].y; }
        }
        if (j < m) {                              // masked final chunk (<8 edges)
            float2 f[4];
#pragma unroll
            for (int u = 0; u < 4; ++u) {
                int e  = j + 2 * u;
                int ce = __builtin_amdgcn_readlane(ci, e < 63 ? e : 63);
                int co = __builtin_amdgcn_readlane(ci, e + 1 < 63 ? e + 1 : 63);
                int c  = pair ? co : ce;
                if (e + pair >= m) c = N;         // dummy zero row
                f[u] = __half22float2(gin[(size_t)c * 32 + lh]);
            }
#pragma unroll
            for (int u = 0; u < 4; ++u) { ax += f[u].x; ay += f[u].y; }
        }
    }

    // merge the two edge-parity halves
    ax += __shfl(ax, lane ^ 32, 64);
    ay += __shfl(ay, lane ^ 32, 64);

    if (pair == 0) {
        float rx = 0.9f * di * (ax + gi.x) + 0.1f * g0v.x;
        float ry = 0.9f * di * (ay + gi.y) + 0.1f * g0v.y;
        if (final_step) {
            float2 bv = ((const float2*)bias)[lh];
            ((float2*)outf)[(size_t)gw * 32 + lh] = make_float2(rx + bv.x, ry + bv.y);
        } else {
            gout[(size_t)gw * 32 + lh] = __floats2half2_rn(di * rx, di * ry);
        }
    }
}

// ---------------- launch ----------------

extern "C" void kernel_launch(void* const* d_in, const int* in_sizes, int n_in,
                              void* d_out, int out_size, void* d_ws, size_t ws_size,
                              hipStream_t stream) {
    const float* x  = (const float*)d_in[0];
    const int*   ei = (const int*)d_in[1];
    const float* W  = (const float*)d_in[2];
    const float* b  = (const float*)d_in[3];
    float* out = (float*)d_out;

    const int N = in_sizes[0] / 128;
    const int E = in_sizes[1] / 2;
    const int* src = ei;
    const int* dst = ei + E;
    const int NB = (N + 255) >> BSH;     // buckets of 256 dsts

    char* w = (char*)d_ws;
    size_t off = 0;
    auto alloc = [&](size_t bytes) -> void* {
        void* p = w + off;
        off += (bytes + 255) & ~(size_t)255;
        return p;
    };
    const size_t fp16buf = (size_t)(N + 1) * 32 * sizeof(__half2);  // 128 B/row
    __half2*  g0h    = (__half2*) alloc(fp16buf);   // +1 dummy row
    __half2*  bufA   = (__half2*) alloc(fp16buf);
    __half2*  bufB   = (__half2*) alloc(fp16buf);
    __half2*  g0f    = (__half2*) alloc(fp16buf);
    int*      cols   = (int*)     alloc((size_t)E * 4);
    unsigned* binned = (unsigned*)alloc((size_t)E * 4);
    int*      rowptr = (int*)     alloc((size_t)(N + 1) * 4);
    int*      counts = (int*)     alloc((size_t)N * 4);
    int*      cursor2= (int*)     alloc((size_t)N * 4);
    int*      bktcur = (int*)     alloc((size_t)NB * 16 * 4);    // 64B-padded
    float*    dinvv  = (float*)   alloc((size_t)N * 4);
    const int nb = (N + 1023) / 1024;
    int*      bsum   = (int*)     alloc((size_t)nb * 4);
    int*      boff   = (int*)     alloc((size_t)nb * 4);

    const int nblkN = (N + 255) / 256;
    const int nblkE = (E + 255) / 256;

    // ---- build plain dst-CSR via binned two-pass ----
    zero_i32<<<nblkN, 256, 0, stream>>>(counts, N);
    hist_k<<<nblkE, 256, 0, stream>>>(dst, E, counts);
    zero_dummy<<<1, 96, 0, stream>>>(g0h, bufA, bufB, N);
    scan_pass1<<<nb, 256, 0, stream>>>(counts, N, bsum);
    scan_pass2<<<1, 256, 0, stream>>>(bsum, nb, boff);
    scan_pass3<<<nb, 256, 0, stream>>>(counts, N, boff, rowptr, E);
    dinv_k<<<nblkN, 256, 0, stream>>>(rowptr, dinvv, N);
    prefill_k<<<nblkN, 256, 0, stream>>>(rowptr, N, NB, cursor2, bktcur);
    binsort_k<<<(E + 4095) / 4096, 256, 0, stream>>>(src, dst, E, bktcur, binned);
    fill2_k<<<NB, 256, 0, stream>>>(binned, rowptr, N, cursor2, cols);

    // g0 = x @ W (propagation commutes with the linear head)
    gemm_k<<<(N + 127) / 128, 256, 0, stream>>>(x, W, dinvv, g0f, g0h, N);

    // K = 10 APPNP steps, fp16 ping-pong; last step writes fp32 d_out (+bias)
    const int nblkP = (N * 64 + 255) / 256;
    const __half2* gin = g0h;
    __half2* pp[2] = {bufA, bufB};
    for (int k = 0; k < 10; ++k) {
        const bool fin = (k == 9);
        __half2* gout = pp[k & 1];
        prop_k<<<nblkP, 256, 0, stream>>>(gin, g0f, gout, out, rowptr, cols,
                                          dinvv, b, N, fin ? 1 : 0);
        gin = gout;
    }
}

// Round 12
// 869.930 us; speedup vs baseline: 1.8379x; 1.1785x over previous
//
#include <hip/hip_runtime.h>
#include <hip/hip_fp16.h>
#include <math.h>

// dst-CSR built with ZERO N-wide passes:
//   bucket_hist_k: LDS-aggregated histogram of 391 buckets (dst>>8).
//   bucket_scan_k: 1-block exclusive scan of bucket totals -> bases/cursors.
//   binsort_k:     bin edges into contiguous bucket runs (rec = src<<8|dst&255).
//   fill2_k:       per bucket: LDS degree count + LDS scan -> rowptr/dinv
//                  (coalesced) + L2-local col[] scatter.
// Propagation unchanged from r11 (full 128B fp16 rows, readlane + paired gathers).

#define BSH 8   // 256 dsts per bucket

// ---------------- small utils ----------------

__global__ void zero_i32(int* __restrict__ p, int n) {
    int i = blockIdx.x * blockDim.x + threadIdx.x;
    if (i < n) p[i] = 0;
}

// zero dummy row N (32 half2) of the three gather buffers
__global__ void zero_dummy(__half2* __restrict__ b0, __half2* __restrict__ b1,
                           __half2* __restrict__ b2, int N) {
    int t = threadIdx.x;
    if (t >= 96) return;
    __half2* b = (t < 32) ? b0 : (t < 64) ? b1 : b2;
    b[(size_t)N * 32 + (t & 31)] = __floats2half2_rn(0.f, 0.f);
}

// ---------------- bucket histogram (LDS-aggregated) ----------------

__global__ void __launch_bounds__(256) bucket_hist_k(const int* __restrict__ dst, int E,
                                                     int* __restrict__ bktcnt) {
    __shared__ int hist[400];
    int t = threadIdx.x;
    for (int i = t; i < 400; i += 256) hist[i] = 0;
    __syncthreads();
    int e0 = blockIdx.x * 4096 + t;
#pragma unroll
    for (int i = 0; i < 16; ++i) {
        int e = e0 + i * 256;
        if (e < E) atomicAdd(&hist[dst[e] >> BSH], 1);
    }
    __syncthreads();
    for (int b = t; b < 400; b += 256) {
        int c = hist[b];
        if (c > 0) atomicAdd(&bktcnt[b], c);
    }
}

// ---------------- 1-block scan of bucket totals -> bases + padded cursors ----------------

__global__ void bucket_scan_k(const int* __restrict__ bktcnt, int nb, int E,
                              int* __restrict__ bktbase, int* __restrict__ bktcur) {
    __shared__ int s[256];
    int t = threadIdx.x;
    int C = (nb + 255) / 256;            // <= 8
    int b0 = t * C;
    int loc[8]; int sum = 0;
    for (int i = 0; i < C; ++i) {
        int v = (b0 + i < nb) ? bktcnt[b0 + i] : 0;
        loc[i] = sum; sum += v;
    }
    s[t] = sum; __syncthreads();
    for (int off = 1; off < 256; off <<= 1) {
        int v = (t >= off) ? s[t - off] : 0;
        __syncthreads();
        s[t] += v;
        __syncthreads();
    }
    int excl = s[t] - sum;
    for (int i = 0; i < C; ++i)
        if (b0 + i < nb) {
            int e0 = excl + loc[i];
            bktbase[b0 + i] = e0;
            bktcur[(b0 + i) * 16] = e0;  // 64B-padded cursor
        }
    if (t == 0) bktbase[nb] = E;
}

// ---------------- bin edges by bucket (dst>>8), contiguous runs ----------------

__global__ void __launch_bounds__(256) binsort_k(const int* __restrict__ src,
                                                 const int* __restrict__ dst, int E,
                                                 int* __restrict__ bktcur,  // padded x16
                                                 unsigned* __restrict__ binned) {
    __shared__ int hist[400], gbase[400], lcur[400];
    int t = threadIdx.x;
    for (int i = t; i < 400; i += 256) { hist[i] = 0; lcur[i] = 0; }
    __syncthreads();

    int e0 = blockIdx.x * 4096 + t;
    unsigned rec[16]; int bk[16];
#pragma unroll
    for (int i = 0; i < 16; ++i) {
        int e = e0 + i * 256;
        if (e < E) {
            int s = src[e], d = dst[e];
            bk[i]  = d >> BSH;
            rec[i] = ((unsigned)s << BSH) | (unsigned)(d & 255);
            atomicAdd(&hist[bk[i]], 1);
        } else bk[i] = -1;
    }
    __syncthreads();
    for (int b = t; b < 400; b += 256) {
        int c = hist[b];
        if (c > 0) gbase[b] = atomicAdd(&bktcur[b * 16], c);
    }
    __syncthreads();
#pragma unroll
    for (int i = 0; i < 16; ++i) {
        if (bk[i] >= 0) {
            int loc = atomicAdd(&lcur[bk[i]], 1);
            binned[gbase[bk[i]] + loc] = rec[i];
        }
    }
}

// ---------------- per-bucket: degrees + rowptr + dinv + col scatter ----------------

__global__ void __launch_bounds__(256) fill2_k(const unsigned* __restrict__ binned,
                                               const int* __restrict__ bktbase,
                                               int N, int E, int NB,
                                               int* __restrict__ rowptr,
                                               float* __restrict__ dinv,
                                               int* __restrict__ col) {
    __shared__ int cnt[256], excl[256], lcur[256];
    int b = blockIdx.x, t = threadIdx.x;
    int beg = bktbase[b], end = bktbase[b + 1];
    cnt[t] = 0;
    __syncthreads();
    for (int i = beg + t; i < end; i += 256)
        atomicAdd(&cnt[binned[i] & 255u], 1);
    __syncthreads();
    int v = cnt[t];
    excl[t] = v;
    __syncthreads();
    for (int off = 1; off < 256; off <<= 1) {
        int u = (t >= off) ? excl[t - off] : 0;
        __syncthreads();
        excl[t] += u;
        __syncthreads();
    }
    int ex = excl[t] - v;                // exclusive prefix within bucket
    lcur[t] = ex;
    int d = (b << BSH) + t;
    if (d < N) {
        rowptr[d] = beg + ex;            // coalesced
        dinv[d] = rsqrtf((float)(v + 1));  // +1 self-loop
    }
    if (b == NB - 1 && t == 0) rowptr[N] = E;
    __syncthreads();
    for (int i = beg + t; i < end; i += 256) {
        unsigned r = binned[i];
        int loc = atomicAdd(&lcur[r & 255u], 1);
        col[beg + loc] = (int)(r >> BSH);   // scatter inside this bucket's segment
    }
}

// ---------------- g0 = x @ W : LDS-tiled ----------------
// Emits TWO fp16 buffers: g0h = dinv[n]*g0[n] (gather state, +dummy row) and
// g0f = g0[n] (teleport term).

__global__ void __launch_bounds__(256) gemm_k(const float* __restrict__ x,
                                              const float* __restrict__ W,
                                              const float* __restrict__ dinv,
                                              __half2* __restrict__ g0f,
                                              __half2* __restrict__ g0h, int N) {
    __shared__ float Ws[128 * 64];
    __shared__ float xs[128 * 133];
    int t = threadIdx.x;
    for (int i = t; i < 128 * 64; i += 256) Ws[i] = W[i];
    int n0 = blockIdx.x * 128;
    for (int f = t; f < 128 * 32; f += 256) {
        int r = f >> 5, c4 = f & 31;
        int n = n0 + r;
        float4 v = (n < N) ? ((const float4*)x)[(size_t)n * 32 + c4]
                           : make_float4(0.f, 0.f, 0.f, 0.f);
        float* dp = &xs[r * 133 + c4 * 4];
        dp[0] = v.x; dp[1] = v.y; dp[2] = v.z; dp[3] = v.w;
    }
    __syncthreads();
    int tr = t & 15, tc = t >> 4;
    int j0 = tr * 4, r0 = tc * 8;
    float acc[8][4] = {};
#pragma unroll 4
    for (int k = 0; k < 128; ++k) {
        float4 wv = *(const float4*)&Ws[k * 64 + j0];
#pragma unroll
        for (int i = 0; i < 8; ++i) {
            float xv = xs[(r0 + i) * 133 + k];
            acc[i][0] += xv * wv.x; acc[i][1] += xv * wv.y;
            acc[i][2] += xv * wv.z; acc[i][3] += xv * wv.w;
        }
    }
    int h0 = j0 >> 1;
#pragma unroll
    for (int i = 0; i < 8; ++i) {
        int n = n0 + r0 + i;
        if (n < N) {
            float dn = dinv[n];
            __half2* gf = &g0f[(size_t)n * 32 + h0];
            gf[0] = __floats2half2_rn(acc[i][0], acc[i][1]);
            gf[1] = __floats2half2_rn(acc[i][2], acc[i][3]);
            __half2* gp = &g0h[(size_t)n * 32 + h0];
            gp[0] = __floats2half2_rn(acc[i][0] * dn, acc[i][1] * dn);
            gp[1] = __floats2half2_rn(acc[i][2] * dn, acc[i][3] * dn);
        }
    }
}

// ---------------- propagation (unchanged from r11) ----------------

__global__ void __launch_bounds__(256) prop_k(const __half2* __restrict__ gin,
                                              const __half2* __restrict__ g0f,
                                              __half2* __restrict__ gout,
                                              float* __restrict__ outf,
                                              const int* __restrict__ rowptr,
                                              const int* __restrict__ cols,
                                              const float* __restrict__ dinv,
                                              const float* __restrict__ bias,
                                              int N, int final_step) {
    int gw = (blockIdx.x * blockDim.x + threadIdx.x) >> 6;
    int lane = threadIdx.x & 63;
    if (gw >= N) return;
    int lh   = lane & 31;   // half2 index within the row
    int pair = lane >> 5;   // 0 = even edge, 1 = odd edge

    int beg = rowptr[gw], end = rowptr[gw + 1];
    int deg = end - beg;

    // hoisted epilogue operands (overlap with gather latency)
    float di   = dinv[gw];
    float2 gi  = __half22float2(gin[(size_t)gw * 32 + lh]);   // self-loop term
    float2 g0v = __half22float2(g0f[(size_t)gw * 32 + lh]);   // teleport term

    float ax = 0.f, ay = 0.f;

    for (int base = 0; base < deg; base += 64) {
        int m = deg - base; if (m > 64) m = 64;
        int idx = beg + base + (lane < m ? lane : 0);
        int ci = cols[idx];                       // 64 edge cols, one load
        int j = 0;
        for (; j + 7 < m; j += 8) {               // 8 edges, 4 paired gathers
            float2 f[4];
#pragma unroll
            for (int u = 0; u < 4; ++u) {
                int ce = __builtin_amdgcn_readlane(ci, j + 2 * u);
                int co = __builtin_amdgcn_readlane(ci, j + 2 * u + 1);
                int c  = pair ? co : ce;
                f[u] = __half22float2(gin[(size_t)c * 32 + lh]);
            }
#pragma unroll
            for (int u = 0; u < 4; ++u) { ax += f[u].x; ay += f[u].y; }
        }
        if (j < m) {                              // masked final chunk (<8 edges)
            float2 f[4];
#pragma unroll
            for (int u = 0; u < 4; ++u) {
                int e  = j + 2 * u;
                int ce = __builtin_amdgcn_readlane(ci, e < 63 ? e : 63);
                int co = __builtin_amdgcn_readlane(ci, e + 1 < 63 ? e + 1 : 63);
                int c  = pair ? co : ce;
                if (e + pair >= m) c = N;         // dummy zero row
                f[u] = __half22float2(gin[(size_t)c * 32 + lh]);
            }
#pragma unroll
            for (int u = 0; u < 4; ++u) { ax += f[u].x; ay += f[u].y; }
        }
    }

    // merge the two edge-parity halves
    ax += __shfl(ax, lane ^ 32, 64);
    ay += __shfl(ay, lane ^ 32, 64);

    if (pair == 0) {
        float rx = 0.9f * di * (ax + gi.x) + 0.1f * g0v.x;
        float ry = 0.9f * di * (ay + gi.y) + 0.1f * g0v.y;
        if (final_step) {
            float2 bv = ((const float2*)bias)[lh];
            ((float2*)outf)[(size_t)gw * 32 + lh] = make_float2(rx + bv.x, ry + bv.y);
        } else {
            gout[(size_t)gw * 32 + lh] = __floats2half2_rn(di * rx, di * ry);
        }
    }
}

// ---------------- launch ----------------

extern "C" void kernel_launch(void* const* d_in, const int* in_sizes, int n_in,
                              void* d_out, int out_size, void* d_ws, size_t ws_size,
                              hipStream_t stream) {
    const float* x  = (const float*)d_in[0];
    const int*   ei = (const int*)d_in[1];
    const float* W  = (const float*)d_in[2];
    const float* b  = (const float*)d_in[3];
    float* out = (float*)d_out;

    const int N = in_sizes[0] / 128;
    const int E = in_sizes[1] / 2;
    const int* src = ei;
    const int* dst = ei + E;
    const int NB = (N + 255) >> BSH;     // buckets of 256 dsts

    char* w = (char*)d_ws;
    size_t off = 0;
    auto alloc = [&](size_t bytes) -> void* {
        void* p = w + off;
        off += (bytes + 255) & ~(size_t)255;
        return p;
    };
    const size_t fp16buf = (size_t)(N + 1) * 32 * sizeof(__half2);  // 128 B/row
    __half2*  g0h    = (__half2*) alloc(fp16buf);   // +1 dummy row
    __half2*  bufA   = (__half2*) alloc(fp16buf);
    __half2*  bufB   = (__half2*) alloc(fp16buf);
    __half2*  g0f    = (__half2*) alloc(fp16buf);
    int*      cols   = (int*)     alloc((size_t)E * 4);
    unsigned* binned = (unsigned*)alloc((size_t)E * 4);
    int*      rowptr = (int*)     alloc((size_t)(N + 1) * 4);
    int*      bktcnt = (int*)     alloc((size_t)NB * 4);
    int*      bktbase= (int*)     alloc((size_t)(NB + 1) * 4);
    int*      bktcur = (int*)     alloc((size_t)NB * 16 * 4);    // 64B-padded
    float*    dinvv  = (float*)   alloc((size_t)N * 4);

    const int nblkB = (E + 4095) / 4096;

    // ---- build dst-CSR: bucket hist -> scan -> binsort -> per-bucket fill ----
    zero_i32<<<(NB + 255) / 256, 256, 0, stream>>>(bktcnt, NB);
    bucket_hist_k<<<nblkB, 256, 0, stream>>>(dst, E, bktcnt);
    zero_dummy<<<1, 96, 0, stream>>>(g0h, bufA, bufB, N);
    bucket_scan_k<<<1, 256, 0, stream>>>(bktcnt, NB, E, bktbase, bktcur);
    binsort_k<<<nblkB, 256, 0, stream>>>(src, dst, E, bktcur, binned);
    fill2_k<<<NB, 256, 0, stream>>>(binned, bktbase, N, E, NB, rowptr, dinvv, cols);

    // g0 = x @ W (propagation commutes with the linear head)
    gemm_k<<<(N + 127) / 128, 256, 0, stream>>>(x, W, dinvv, g0f, g0h, N);

    // K = 10 APPNP steps, fp16 ping-pong; last step writes fp32 d_out (+bias)
    const int nblkP = (N * 64 + 255) / 256;
    const __half2* gin = g0h;
    __half2* pp[2] = {bufA, bufB};
    for (int k = 0; k < 10; ++k) {
        const bool fin = (k == 9);
        __half2* gout = pp[k & 1];
        prop_k<<<nblkP, 256, 0, stream>>>(gin, g0f, gout, out, rowptr, cols,
                                          dinvv, b, N, fin ? 1 : 0);
        gin = gout;
    }
}